// Round 2
// baseline (907.345 us; speedup 1.0000x reference)
//
#include <hip/hip_runtime.h>
#include <hip/hip_bf16.h>

typedef __attribute__((ext_vector_type(8))) short bf16x8;
typedef __attribute__((ext_vector_type(4))) float f32x4;

#define N_NODES_C 100000
#define N_EDGES_C 1600000
#define NUM_REL_C 64
#define DIM_C 128

static __device__ __forceinline__ unsigned short f32_to_bf16(float f) {
    unsigned int u = __float_as_uint(f);
    unsigned int r = (u + 0x7FFFu + ((u >> 16) & 1u)) >> 16;
    return (unsigned short)r;
}

static __device__ __forceinline__ bf16x8 pack8(const float* p) {
    float4 a = *(const float4*)p;
    float4 b = *(const float4*)(p + 4);
    bf16x8 v;
    v[0] = (short)f32_to_bf16(a.x); v[1] = (short)f32_to_bf16(a.y);
    v[2] = (short)f32_to_bf16(a.z); v[3] = (short)f32_to_bf16(a.w);
    v[4] = (short)f32_to_bf16(b.x); v[5] = (short)f32_to_bf16(b.y);
    v[6] = (short)f32_to_bf16(b.z); v[7] = (short)f32_to_bf16(b.w);
    return v;
}

// ---------------- binning ----------------

__global__ void hist_kernel(const int* __restrict__ et, int* __restrict__ cnt, int E) {
    __shared__ int h[NUM_REL_C];
    if (threadIdx.x < NUM_REL_C) h[threadIdx.x] = 0;
    __syncthreads();
    for (int e = blockIdx.x * blockDim.x + threadIdx.x; e < E; e += gridDim.x * blockDim.x)
        atomicAdd(&h[et[e]], 1);
    __syncthreads();
    if (threadIdx.x < NUM_REL_C && h[threadIdx.x] > 0)
        atomicAdd(&cnt[threadIdx.x], h[threadIdx.x]);
}

__global__ void scan_kernel(const int* __restrict__ cnt, int* __restrict__ relOff,
                            int* __restrict__ tileOff, int* __restrict__ cursor) {
    // single thread: 64 entries
    int ro = 0, to = 0;
    for (int r = 0; r < NUM_REL_C; r++) {
        relOff[r] = ro; cursor[r] = ro; tileOff[r] = to;
        ro += cnt[r];
        to += (cnt[r] + 15) >> 4;
    }
    relOff[NUM_REL_C] = ro;
    tileOff[NUM_REL_C] = to;
}

#define SCAT_CHUNK 6250
__global__ void scatter_kernel(const int* __restrict__ et, int* __restrict__ cursor,
                               int* __restrict__ sorted, int E) {
    __shared__ int h[NUM_REL_C], base[NUM_REL_C], h2[NUM_REL_C];
    int tid = threadIdx.x;
    if (tid < NUM_REL_C) { h[tid] = 0; h2[tid] = 0; }
    __syncthreads();
    int begin = blockIdx.x * SCAT_CHUNK;
    int end = min(begin + SCAT_CHUNK, E);
    for (int e = begin + tid; e < end; e += blockDim.x)
        atomicAdd(&h[et[e]], 1);
    __syncthreads();
    if (tid < NUM_REL_C && h[tid] > 0)
        base[tid] = atomicAdd(&cursor[tid], h[tid]);
    __syncthreads();
    for (int e = begin + tid; e < end; e += blockDim.x) {
        int r = et[e];
        int p = base[r] + atomicAdd(&h2[r], 1);
        sorted[p] = e;
    }
}

// ---------------- weight prep ----------------

// Wt[r][j][i] = bf16( sum_b w_coe[r][b] * weight[b][i][j] )  (transposed for B-frag loads)
__global__ void build_wrel(const float* __restrict__ weight, const float* __restrict__ w_coe,
                           unsigned short* __restrict__ Wt) {
    int idx = blockIdx.x * blockDim.x + threadIdx.x;  // 64*128*128 threads, j fastest
    int r = idx >> 14;
    int i = (idx >> 7) & 127;
    int j = idx & 127;
    float s = 0.f;
#pragma unroll
    for (int b = 0; b < 8; b++)
        s += w_coe[r * 8 + b] * weight[b * (DIM_C * DIM_C) + i * DIM_C + j];
    Wt[r * (DIM_C * DIM_C) + j * DIM_C + i] = f32_to_bf16(s);
}

// slt[j][i] = bf16(self_loop[i][j])
__global__ void build_slt(const float* __restrict__ sl, unsigned short* __restrict__ slt) {
    int idx = blockIdx.x * blockDim.x + threadIdx.x;  // 16384
    int i = idx >> 7, j = idx & 127;
    slt[j * DIM_C + i] = f32_to_bf16(sl[i * DIM_C + j]);
}

// ---------------- self-loop GEMM: out = X @ self_loop ----------------

__global__ __launch_bounds__(256) void selfloop_gemm(const float* __restrict__ X,
                                                     const unsigned short* __restrict__ slt,
                                                     float* __restrict__ out) {
    int wid = blockIdx.x * 4 + (threadIdx.x >> 6);
    if (wid >= N_NODES_C / 16) return;
    int lane = threadIdx.x & 63;
    int row = lane & 15;          // A row within 16-node tile
    int col0 = lane & 15;         // B/D col
    int khi = (lane >> 4) * 8;    // k sub-offset for A/B frags
    const float* xrow = X + (size_t)(wid * 16 + row) * DIM_C;

    bf16x8 a[4];
#pragma unroll
    for (int ks = 0; ks < 4; ks++) a[ks] = pack8(xrow + ks * 32 + khi);

    f32x4 acc[8];
#pragma unroll
    for (int cb = 0; cb < 8; cb++) acc[cb] = (f32x4)0.0f;

#pragma unroll
    for (int cb = 0; cb < 8; cb++) {
#pragma unroll
        for (int ks = 0; ks < 4; ks++) {
            bf16x8 b = *(const bf16x8*)(slt + (size_t)(cb * 16 + col0) * DIM_C + ks * 32 + khi);
            acc[cb] = __builtin_amdgcn_mfma_f32_16x16x32_bf16(a[ks], b, acc[cb], 0, 0, 0);
        }
    }
    // D: col = lane&15, row = (lane>>4)*4 + j
    int rg = lane >> 4;
#pragma unroll
    for (int j = 0; j < 4; j++) {
        float* op = out + (size_t)(wid * 16 + rg * 4 + j) * DIM_C + col0;
#pragma unroll
        for (int cb = 0; cb < 8; cb++) op[cb * 16] = acc[cb][j];
    }
}

// ---------------- edge GEMM + scatter ----------------

__global__ __launch_bounds__(256) void edge_gemm(const float* __restrict__ X,
                                                 const unsigned short* __restrict__ Wt,
                                                 const float* __restrict__ norm,
                                                 const int* __restrict__ src,
                                                 const int* __restrict__ dst,
                                                 const int* __restrict__ sorted,
                                                 const int* __restrict__ relOff,
                                                 const int* __restrict__ tileOff,
                                                 float* __restrict__ out) {
    int wid = blockIdx.x * 4 + (threadIdx.x >> 6);
    int totalTiles = tileOff[NUM_REL_C];
    if (wid >= totalTiles) return;
    int lane = threadIdx.x & 63;

    // find relation r: tileOff[r] <= wid < tileOff[r+1]
    int lo = 0, hi = NUM_REL_C;
    while (hi - lo > 1) {
        int mid = (lo + hi) >> 1;
        if (tileOff[mid] <= wid) lo = mid; else hi = mid;
    }
    int r = lo;
    int start = relOff[r] + (wid - tileOff[r]) * 16;
    int cnt = min(16, relOff[r + 1] - start);

    int row = lane & 15;
    int col0 = lane & 15;
    int khi = (lane >> 4) * 8;

    int e = sorted[start + min(row, cnt - 1)];
    const float* xrow = X + (size_t)src[e] * DIM_C;

    bf16x8 a[4];
#pragma unroll
    for (int ks = 0; ks < 4; ks++) a[ks] = pack8(xrow + ks * 32 + khi);

    const unsigned short* WR = Wt + (size_t)r * (DIM_C * DIM_C);
    f32x4 acc[8];
#pragma unroll
    for (int cb = 0; cb < 8; cb++) acc[cb] = (f32x4)0.0f;

#pragma unroll
    for (int cb = 0; cb < 8; cb++) {
#pragma unroll
        for (int ks = 0; ks < 4; ks++) {
            bf16x8 b = *(const bf16x8*)(WR + (size_t)(cb * 16 + col0) * DIM_C + ks * 32 + khi);
            acc[cb] = __builtin_amdgcn_mfma_f32_16x16x32_bf16(a[ks], b, acc[cb], 0, 0, 0);
        }
    }

    // D: col = col0 + cb*16, row (edge slot) = (lane>>4)*4 + j
    int rg = lane >> 4;
#pragma unroll
    for (int j = 0; j < 4; j++) {
        int orow = rg * 4 + j;
        if (orow < cnt) {
            int ee = sorted[start + orow];          // broadcast within 16-lane group
            float nr = norm[ee];
            float* op = out + (size_t)dst[ee] * DIM_C + col0;
#pragma unroll
            for (int cb = 0; cb < 8; cb++)
                atomicAdd(op + cb * 16, acc[cb][j] * nr);
        }
    }
}

// ---------------- launch ----------------

extern "C" void kernel_launch(void* const* d_in, const int* in_sizes, int n_in,
                              void* d_out, int out_size, void* d_ws, size_t ws_size,
                              hipStream_t stream) {
    const float* node_feat = (const float*)d_in[0];
    const float* weight    = (const float*)d_in[1];
    const float* w_coe     = (const float*)d_in[2];
    const float* self_loop = (const float*)d_in[3];
    const float* norm      = (const float*)d_in[4];
    const int*   src       = (const int*)d_in[5];
    const int*   dst       = (const int*)d_in[6];
    const int*   etype     = (const int*)d_in[7];
    float* out = (float*)d_out;

    char* ws = (char*)d_ws;
    int* cnt     = (int*)(ws + 0);
    int* cursor  = (int*)(ws + 256);
    int* relOff  = (int*)(ws + 512);
    int* tileOff = (int*)(ws + 1024);
    int* sorted  = (int*)(ws + 4096);
    size_t o = 4096 + (size_t)N_EDGES_C * 4;
    o = (o + 255) & ~(size_t)255;
    unsigned short* Wt  = (unsigned short*)(ws + o);
    unsigned short* slt = (unsigned short*)(ws + o + (size_t)NUM_REL_C * DIM_C * DIM_C * 2);

    hipMemsetAsync(cnt, 0, 256, stream);
    hist_kernel<<<1024, 256, 0, stream>>>(etype, cnt, N_EDGES_C);
    scan_kernel<<<1, 1, 0, stream>>>(cnt, relOff, tileOff, cursor);
    scatter_kernel<<<256, 256, 0, stream>>>(etype, cursor, sorted, N_EDGES_C);
    build_wrel<<<4096, 256, 0, stream>>>(weight, w_coe, Wt);
    build_slt<<<64, 256, 0, stream>>>(self_loop, slt);
    selfloop_gemm<<<(N_NODES_C / 16 + 3) / 4, 256, 0, stream>>>(node_feat, slt, out);

    int maxTiles = N_EDGES_C / 16 + NUM_REL_C;  // upper bound on sum of per-rel ceils
    edge_gemm<<<(maxTiles + 3) / 4, 256, 0, stream>>>(node_feat, Wt, norm, src, dst,
                                                      sorted, relOff, tileOff, out);
}

// Round 6
// 745.807 us; speedup vs baseline: 1.2166x; 1.2166x over previous
//
#include <hip/hip_runtime.h>
#include <hip/hip_bf16.h>

typedef __attribute__((ext_vector_type(8))) short bf16x8;
typedef __attribute__((ext_vector_type(4))) float f32x4;

#define NN 100000
#define NE 1600000
#define DIM 128
#define KTOT 1152          // 8*128 (bases) + 128 (self-loop)
#define SCAN_B 391         // ceil(NN/256)

static __device__ __forceinline__ unsigned short f32_to_bf16(float f) {
    unsigned int u = __float_as_uint(f);
    unsigned int r = (u + 0x7FFFu + ((u >> 16) & 1u)) >> 16;
    return (unsigned short)r;
}

// ---------------- dst counting sort ----------------

__global__ void histD_kernel(const int* __restrict__ dst, int* __restrict__ hist) {
    for (int e = blockIdx.x * blockDim.x + threadIdx.x; e < NE; e += gridDim.x * blockDim.x)
        atomicAdd(&hist[dst[e]], 1);
}

__global__ void scanA_kernel(const int* __restrict__ hist, int* __restrict__ incl,
                             int* __restrict__ bsum) {
    __shared__ int s[256];
    int t = threadIdx.x, i = blockIdx.x * 256 + t;
    int v = (i < NN) ? hist[i] : 0;
    s[t] = v; __syncthreads();
    for (int o = 1; o < 256; o <<= 1) {
        int x = (t >= o) ? s[t - o] : 0;
        __syncthreads();
        s[t] += x;
        __syncthreads();
    }
    if (i < NN) incl[i] = s[t];
    if (t == 255) bsum[blockIdx.x] = s[255];
}

__global__ void scanB_kernel(const int* __restrict__ bsum, int* __restrict__ boff) {
    __shared__ int s[512];
    int t = threadIdx.x;
    int v = (t < SCAN_B) ? bsum[t] : 0;
    s[t] = v; __syncthreads();
    for (int o = 1; o < 512; o <<= 1) {
        int x = (t >= o) ? s[t - o] : 0;
        __syncthreads();
        s[t] += x;
        __syncthreads();
    }
    if (t < SCAN_B) boff[t] = s[t] - v;   // exclusive
}

__global__ void scanC_kernel(const int* __restrict__ hist, const int* __restrict__ incl,
                             const int* __restrict__ boff, int* __restrict__ dstOff,
                             int* __restrict__ cursor) {
    int i = blockIdx.x * 256 + threadIdx.x;
    if (i >= NN) return;
    int ex = incl[i] - hist[i] + boff[blockIdx.x];
    dstOff[i] = ex; cursor[i] = ex;
    if (i == NN - 1) dstOff[NN] = boff[blockIdx.x] + incl[i];
}

// rec[p] = {src | etype<<20, norm} in dst-sorted order
__global__ void scatterD_kernel(const int* __restrict__ src, const int* __restrict__ dst,
                                const int* __restrict__ et, const float* __restrict__ norm,
                                int* __restrict__ cursor, int2* __restrict__ rec) {
    for (int e = blockIdx.x * blockDim.x + threadIdx.x; e < NE; e += gridDim.x * blockDim.x) {
        int d = dst[e];
        int p = atomicAdd(&cursor[d], 1);
        rec[p] = make_int2(src[e] | (et[e] << 20), __float_as_int(norm[e]));
    }
}

// ---------------- precompute ----------------

__global__ void xbf16_kernel(const float* __restrict__ X, unsigned int* __restrict__ Xb) {
    int i = blockIdx.x * 256 + threadIdx.x;   // NN*64 pairs
    if (i >= NN * 64) return;
    float2 v = ((const float2*)X)[i];
    Xb[i] = (unsigned int)f32_to_bf16(v.x) | ((unsigned int)f32_to_bf16(v.y) << 16);
}

// Bt[j][k]: k<1024 -> weight[b=k>>7][i=k&127][j]; k>=1024 -> self_loop[k-1024][j]
__global__ void buildBt_kernel(const float* __restrict__ weight, const float* __restrict__ sl,
                               unsigned short* __restrict__ Bt) {
    int idx = blockIdx.x * 256 + threadIdx.x;  // 128*1152
    if (idx >= 128 * KTOT) return;
    int j = idx / KTOT;
    int k = idx - j * KTOT;
    float v;
    if (k < 1024) { int b = k >> 7, i = k & 127; v = weight[(b << 14) + (i << 7) + j]; }
    else          { int i = k - 1024;            v = sl[(i << 7) + j]; }
    Bt[j * KTOT + k] = f32_to_bf16(v);
}

// ---------------- per-dst aggregation: A[d - c0][b*128 + i] ----------------

__global__ __launch_bounds__(256) void aggregate_kernel(const int2* __restrict__ rec,
        const int* __restrict__ dstOff, const unsigned int* __restrict__ Xb,
        const float* __restrict__ w_coe, unsigned int* __restrict__ A, int c0, int C) {
    int wid = blockIdx.x * 4 + (threadIdx.x >> 6);
    if (wid >= C) return;
    int d = c0 + wid;
    int lane = threadIdx.x & 63;        // lane covers cols 2*lane, 2*lane+1

    float acc0[8], acc1[8];
#pragma unroll
    for (int b = 0; b < 8; b++) { acc0[b] = 0.f; acc1[b] = 0.f; }

    int q1 = dstOff[d + 1];
    for (int q = dstOff[d]; q < q1; q++) {
        int2 rc = rec[q];                               // wave-uniform
        int s = rc.x & 0xFFFFF;
        int r = rc.x >> 20;
        float nr = __int_as_float(rc.y);
        unsigned int xu = Xb[(s << 6) + lane];
        float x0 = __uint_as_float(xu << 16);
        float x1 = __uint_as_float(xu & 0xFFFF0000u);
        const float* wc = w_coe + (r << 3);
#pragma unroll
        for (int b = 0; b < 8; b++) {
            float c = wc[b] * nr;
            acc0[b] += c * x0;
            acc1[b] += c * x1;
        }
    }
#pragma unroll
    for (int b = 0; b < 8; b++) {
        unsigned int pk = (unsigned int)f32_to_bf16(acc0[b]) |
                          ((unsigned int)f32_to_bf16(acc1[b]) << 16);
        A[(size_t)wid * 512 + b * 64 + lane] = pk;
    }
}

// ---------------- dense GEMM: out[16 rows] = [A | Xb] @ Bt ----------------

__global__ __launch_bounds__(256) void gemm_kernel(const unsigned short* __restrict__ A,
        const unsigned short* __restrict__ Xb16, const unsigned short* __restrict__ Bt,
        float* __restrict__ out, int c0, int nTiles) {
    int wid = blockIdx.x * 4 + (threadIdx.x >> 6);
    if (wid >= nTiles) return;
    int lane = threadIdx.x & 63;
    int row = lane & 15, col0 = lane & 15, khi = (lane >> 4) * 8;

    const unsigned short* arow = A + ((size_t)(wid * 16 + row) << 10);          // local rows, *1024
    const unsigned short* xrow = Xb16 + ((size_t)(c0 + wid * 16 + row) << 7);   // global rows, *128

    f32x4 acc[8];
#pragma unroll
    for (int cb = 0; cb < 8; cb++) acc[cb] = (f32x4)0.0f;

#pragma unroll
    for (int ks = 0; ks < 36; ks++) {
        bf16x8 a = (ks < 32) ? *(const bf16x8*)(arow + ks * 32 + khi)
                             : *(const bf16x8*)(xrow + (ks - 32) * 32 + khi);
        const unsigned short* bp = Bt + ks * 32 + khi;
#pragma unroll
        for (int cb = 0; cb < 8; cb++) {
            bf16x8 b = *(const bf16x8*)(bp + (size_t)(col0 + cb * 16) * KTOT);
            acc[cb] = __builtin_amdgcn_mfma_f32_16x16x32_bf16(a, b, acc[cb], 0, 0, 0);
        }
    }

    int rg = lane >> 4;
#pragma unroll
    for (int j = 0; j < 4; j++) {
        float* op = out + (size_t)(c0 + wid * 16 + rg * 4 + j) * DIM + col0;
#pragma unroll
        for (int cb = 0; cb < 8; cb++) op[cb * 16] = acc[cb][j];
    }
}

// ---------------- launch ----------------

extern "C" void kernel_launch(void* const* d_in, const int* in_sizes, int n_in,
                              void* d_out, int out_size, void* d_ws, size_t ws_size,
                              hipStream_t stream) {
    const float* node_feat = (const float*)d_in[0];
    const float* weight    = (const float*)d_in[1];
    const float* w_coe     = (const float*)d_in[2];
    const float* self_loop = (const float*)d_in[3];
    const float* norm      = (const float*)d_in[4];
    const int*   src       = (const int*)d_in[5];
    const int*   dst       = (const int*)d_in[6];
    const int*   etype     = (const int*)d_in[7];
    float* out = (float*)d_out;

    char* ws = (char*)d_ws;
    size_t off = 0;
    auto take = [&](size_t bytes) { size_t o = off; off = (off + bytes + 255) & ~(size_t)255; return o; };

    int* dstOff = (int*)(ws + take((NN + 1) * 4));
    int* cursor = (int*)(ws + take((size_t)NN * 4));
    int* hist   = (int*)(ws + take((size_t)NN * 4));
    int* incl   = (int*)(ws + take((size_t)NN * 4));
    int* bsum   = (int*)(ws + take(SCAN_B * 4));
    int* boff   = (int*)(ws + take(SCAN_B * 4));
    int2* rec   = (int2*)(ws + take((size_t)NE * 8));
    unsigned int* Xb = (unsigned int*)(ws + take((size_t)NN * 64 * 4));
    unsigned short* Bt = (unsigned short*)(ws + take((size_t)128 * KTOT * 2));

    size_t avail = (ws_size > off) ? ws_size - off : 0;
    long long cc = (long long)(avail / 2048);   // 2KB per A row
    cc &= ~15LL;
    if (cc > NN) cc = NN;
    if (cc < 16) cc = 16;
    int chunkC = (int)cc;
    unsigned int* A = (unsigned int*)(ws + off);

    hipMemsetAsync(hist, 0, (size_t)NN * 4, stream);
    histD_kernel<<<1024, 256, 0, stream>>>(dst, hist);
    scanA_kernel<<<SCAN_B, 256, 0, stream>>>(hist, incl, bsum);
    scanB_kernel<<<1, 512, 0, stream>>>(bsum, boff);
    scanC_kernel<<<SCAN_B, 256, 0, stream>>>(hist, incl, boff, dstOff, cursor);
    scatterD_kernel<<<1024, 256, 0, stream>>>(src, dst, etype, norm, cursor, rec);
    xbf16_kernel<<<(NN * 64 + 255) / 256, 256, 0, stream>>>(node_feat, Xb);
    buildBt_kernel<<<(128 * KTOT + 255) / 256, 256, 0, stream>>>(weight, self_loop, Bt);

    for (int c0 = 0; c0 < NN; c0 += chunkC) {
        int C = NN - c0; if (C > chunkC) C = chunkC;
        aggregate_kernel<<<(C + 3) / 4, 256, 0, stream>>>(rec, dstOff, Xb, w_coe, A, c0, C);
        int nT = C / 16;
        gemm_kernel<<<(nT + 3) / 4, 256, 0, stream>>>((const unsigned short*)A,
                (const unsigned short*)Xb, Bt, out, c0, nT);
    }
}

// Round 10
// 526.800 us; speedup vs baseline: 1.7224x; 1.4157x over previous
//
#include <hip/hip_runtime.h>
#include <hip/hip_bf16.h>

typedef __attribute__((ext_vector_type(8))) short bf16x8;
typedef __attribute__((ext_vector_type(4))) float f32x4;

#define NN 100000
#define NE 1600000
#define DIM 128
#define KTOT 1152          // 8*128 (bases) + 128 (self-loop)
#define SCAN_B 391         // ceil(NN/256)

static __device__ __forceinline__ unsigned short f32_to_bf16(float f) {
    unsigned int u = __float_as_uint(f);
    unsigned int r = (u + 0x7FFFu + ((u >> 16) & 1u)) >> 16;
    return (unsigned short)r;
}

// ---------------- dst counting sort ----------------

__global__ void histD_kernel(const int* __restrict__ dst, int* __restrict__ hist) {
    for (int e = blockIdx.x * blockDim.x + threadIdx.x; e < NE; e += gridDim.x * blockDim.x)
        atomicAdd(&hist[dst[e]], 1);
}

__global__ void scanA_kernel(const int* __restrict__ hist, int* __restrict__ incl,
                             int* __restrict__ bsum) {
    __shared__ int s[256];
    int t = threadIdx.x, i = blockIdx.x * 256 + t;
    int v = (i < NN) ? hist[i] : 0;
    s[t] = v; __syncthreads();
    for (int o = 1; o < 256; o <<= 1) {
        int x = (t >= o) ? s[t - o] : 0;
        __syncthreads();
        s[t] += x;
        __syncthreads();
    }
    if (i < NN) incl[i] = s[t];
    if (t == 255) bsum[blockIdx.x] = s[255];
}

__global__ void scanB_kernel(const int* __restrict__ bsum, int* __restrict__ boff) {
    __shared__ int s[512];
    int t = threadIdx.x;
    int v = (t < SCAN_B) ? bsum[t] : 0;
    s[t] = v; __syncthreads();
    for (int o = 1; o < 512; o <<= 1) {
        int x = (t >= o) ? s[t - o] : 0;
        __syncthreads();
        s[t] += x;
        __syncthreads();
    }
    if (t < SCAN_B) boff[t] = s[t] - v;   // exclusive
}

__global__ void scanC_kernel(const int* __restrict__ hist, const int* __restrict__ incl,
                             const int* __restrict__ boff, int* __restrict__ dstOff,
                             int* __restrict__ cursor) {
    int i = blockIdx.x * 256 + threadIdx.x;
    if (i >= NN) return;
    int ex = incl[i] - hist[i] + boff[blockIdx.x];
    dstOff[i] = ex; cursor[i] = ex;
    if (i == NN - 1) dstOff[NN] = boff[blockIdx.x] + incl[i];
}

// rec[p] = {src | etype<<20, norm} in dst-sorted order
__global__ void scatterD_kernel(const int* __restrict__ src, const int* __restrict__ dst,
                                const int* __restrict__ et, const float* __restrict__ norm,
                                int* __restrict__ cursor, int2* __restrict__ rec) {
    for (int e = blockIdx.x * blockDim.x + threadIdx.x; e < NE; e += gridDim.x * blockDim.x) {
        int d = dst[e];
        int p = atomicAdd(&cursor[d], 1);
        rec[p] = make_int2(src[e] | (et[e] << 20), __float_as_int(norm[e]));
    }
}

// ---------------- precompute ----------------

__global__ void xbf16_kernel(const float* __restrict__ X, unsigned int* __restrict__ Xb) {
    int i = blockIdx.x * 256 + threadIdx.x;   // NN*64 pairs
    if (i >= NN * 64) return;
    float2 v = ((const float2*)X)[i];
    Xb[i] = (unsigned int)f32_to_bf16(v.x) | ((unsigned int)f32_to_bf16(v.y) << 16);
}

// Bt[j][k]: k<1024 -> weight[b=k>>7][i=k&127][j]; k>=1024 -> self_loop[k-1024][j]
__global__ void buildBt_kernel(const float* __restrict__ weight, const float* __restrict__ sl,
                               unsigned short* __restrict__ Bt) {
    int idx = blockIdx.x * 256 + threadIdx.x;  // 128*1152
    if (idx >= 128 * KTOT) return;
    int j = idx / KTOT;
    int k = idx - j * KTOT;
    float v;
    if (k < 1024) { int b = k >> 7, i = k & 127; v = weight[(b << 14) + (i << 7) + j]; }
    else          { int i = k - 1024;            v = sl[(i << 7) + j]; }
    Bt[j * KTOT + k] = f32_to_bf16(v);
}

// ---------------- per-dst aggregation: A[d - c0][b*128 + i] ----------------
// w_coe staged in LDS (removes 8 global loads/edge); edge loop unrolled x2
// with dual accumulator banks to double the rec->Xb dependent-load MLP.

__global__ __launch_bounds__(256) void aggregate_kernel(const int2* __restrict__ rec,
        const int* __restrict__ dstOff, const unsigned int* __restrict__ Xb,
        const float* __restrict__ w_coe, unsigned int* __restrict__ A, int c0, int C) {
    __shared__ float swc[512];                 // 64 rel x 8 bases
    swc[threadIdx.x] = w_coe[threadIdx.x];
    swc[threadIdx.x + 256] = w_coe[threadIdx.x + 256];
    __syncthreads();

    int wid = blockIdx.x * 4 + (threadIdx.x >> 6);
    if (wid >= C) return;
    int d = c0 + wid;
    int lane = threadIdx.x & 63;        // lane covers cols 2*lane, 2*lane+1

    float acc0[8], acc1[8], bcc0[8], bcc1[8];
#pragma unroll
    for (int b = 0; b < 8; b++) { acc0[b] = 0.f; acc1[b] = 0.f; bcc0[b] = 0.f; bcc1[b] = 0.f; }

    int q = dstOff[d], q1 = dstOff[d + 1];
    for (; q + 2 <= q1; q += 2) {
        int2 rcA = rec[q];
        int2 rcB = rec[q + 1];
        int sA = rcA.x & 0xFFFFF, rA = rcA.x >> 20;
        int sB = rcB.x & 0xFFFFF, rB = rcB.x >> 20;
        unsigned int xuA = Xb[(sA << 6) + lane];
        unsigned int xuB = Xb[(sB << 6) + lane];
        float nrA = __int_as_float(rcA.y);
        float nrB = __int_as_float(rcB.y);
        float xA0 = __uint_as_float(xuA << 16);
        float xA1 = __uint_as_float(xuA & 0xFFFF0000u);
        float xB0 = __uint_as_float(xuB << 16);
        float xB1 = __uint_as_float(xuB & 0xFFFF0000u);
        const float* wcA = swc + (rA << 3);
        const float* wcB = swc + (rB << 3);
#pragma unroll
        for (int b = 0; b < 8; b++) {
            float cA = wcA[b] * nrA;
            float cB = wcB[b] * nrB;
            acc0[b] += cA * xA0;
            acc1[b] += cA * xA1;
            bcc0[b] += cB * xB0;
            bcc1[b] += cB * xB1;
        }
    }
    if (q < q1) {
        int2 rc = rec[q];
        int s = rc.x & 0xFFFFF, r = rc.x >> 20;
        float nr = __int_as_float(rc.y);
        unsigned int xu = Xb[(s << 6) + lane];
        float x0 = __uint_as_float(xu << 16);
        float x1 = __uint_as_float(xu & 0xFFFF0000u);
        const float* wc = swc + (r << 3);
#pragma unroll
        for (int b = 0; b < 8; b++) {
            float c = wc[b] * nr;
            acc0[b] += c * x0;
            acc1[b] += c * x1;
        }
    }
#pragma unroll
    for (int b = 0; b < 8; b++) {
        unsigned int pk = (unsigned int)f32_to_bf16(acc0[b] + bcc0[b]) |
                          ((unsigned int)f32_to_bf16(acc1[b] + bcc1[b]) << 16);
        A[(size_t)wid * 512 + b * 64 + lane] = pk;
    }
}

// ---------------- dense GEMM: out[64 rows/wave] = [A | Xb] @ Bt ----------------
// Each wave: M=64 (4 row-tiles), full N=128 (8 col-blocks). B-frag reuse x4.

__global__ __launch_bounds__(256, 2) void gemm_kernel(const unsigned short* __restrict__ A,
        const unsigned short* __restrict__ Xb16, const unsigned short* __restrict__ Bt,
        float* __restrict__ out, int c0, int nW, int C) {
    int wid = blockIdx.x * 4 + (threadIdx.x >> 6);
    if (wid >= nW) return;
    int lane = threadIdx.x & 63;
    int col0 = lane & 15, khi = (lane >> 4) * 8;
    int r0 = wid * 64;                       // local row base of this wave's 64 rows

    const unsigned short* arow[4];
    const unsigned short* xrow[4];
#pragma unroll
    for (int m = 0; m < 4; m++) {
        int lrow = r0 + m * 16 + col0;                  // A rows padded to 64-mult (safe)
        arow[m] = A + ((size_t)lrow << 10);
        int grow = c0 + lrow; if (grow > NN - 1) grow = NN - 1;   // clamp tail reads
        xrow[m] = Xb16 + ((size_t)grow << 7);
    }

    f32x4 acc[4][8];
#pragma unroll
    for (int m = 0; m < 4; m++)
#pragma unroll
        for (int cb = 0; cb < 8; cb++) acc[m][cb] = (f32x4)0.0f;

    // K = 0..1023 from A
#pragma unroll 4
    for (int ks = 0; ks < 32; ks++) {
        bf16x8 a0 = *(const bf16x8*)(arow[0] + ks * 32 + khi);
        bf16x8 a1 = *(const bf16x8*)(arow[1] + ks * 32 + khi);
        bf16x8 a2 = *(const bf16x8*)(arow[2] + ks * 32 + khi);
        bf16x8 a3 = *(const bf16x8*)(arow[3] + ks * 32 + khi);
        const unsigned short* bp = Bt + ks * 32 + khi;
#pragma unroll
        for (int cb = 0; cb < 8; cb++) {
            bf16x8 b = *(const bf16x8*)(bp + (size_t)(col0 + cb * 16) * KTOT);
            acc[0][cb] = __builtin_amdgcn_mfma_f32_16x16x32_bf16(a0, b, acc[0][cb], 0, 0, 0);
            acc[1][cb] = __builtin_amdgcn_mfma_f32_16x16x32_bf16(a1, b, acc[1][cb], 0, 0, 0);
            acc[2][cb] = __builtin_amdgcn_mfma_f32_16x16x32_bf16(a2, b, acc[2][cb], 0, 0, 0);
            acc[3][cb] = __builtin_amdgcn_mfma_f32_16x16x32_bf16(a3, b, acc[3][cb], 0, 0, 0);
        }
    }
    // K = 1024..1151 from Xb (self-loop columns)
#pragma unroll
    for (int ks = 32; ks < 36; ks++) {
        bf16x8 a0 = *(const bf16x8*)(xrow[0] + (ks - 32) * 32 + khi);
        bf16x8 a1 = *(const bf16x8*)(xrow[1] + (ks - 32) * 32 + khi);
        bf16x8 a2 = *(const bf16x8*)(xrow[2] + (ks - 32) * 32 + khi);
        bf16x8 a3 = *(const bf16x8*)(xrow[3] + (ks - 32) * 32 + khi);
        const unsigned short* bp = Bt + ks * 32 + khi;
#pragma unroll
        for (int cb = 0; cb < 8; cb++) {
            bf16x8 b = *(const bf16x8*)(bp + (size_t)(col0 + cb * 16) * KTOT);
            acc[0][cb] = __builtin_amdgcn_mfma_f32_16x16x32_bf16(a0, b, acc[0][cb], 0, 0, 0);
            acc[1][cb] = __builtin_amdgcn_mfma_f32_16x16x32_bf16(a1, b, acc[1][cb], 0, 0, 0);
            acc[2][cb] = __builtin_amdgcn_mfma_f32_16x16x32_bf16(a2, b, acc[2][cb], 0, 0, 0);
            acc[3][cb] = __builtin_amdgcn_mfma_f32_16x16x32_bf16(a3, b, acc[3][cb], 0, 0, 0);
        }
    }

    int rg = lane >> 4;
#pragma unroll
    for (int m = 0; m < 4; m++) {
#pragma unroll
        for (int j = 0; j < 4; j++) {
            int lrow = r0 + m * 16 + rg * 4 + j;
            if (lrow < C) {
                float* op = out + (size_t)(c0 + lrow) * DIM + col0;
#pragma unroll
                for (int cb = 0; cb < 8; cb++) op[cb * 16] = acc[m][cb][j];
            }
        }
    }
}

// ---------------- launch ----------------

extern "C" void kernel_launch(void* const* d_in, const int* in_sizes, int n_in,
                              void* d_out, int out_size, void* d_ws, size_t ws_size,
                              hipStream_t stream) {
    const float* node_feat = (const float*)d_in[0];
    const float* weight    = (const float*)d_in[1];
    const float* w_coe     = (const float*)d_in[2];
    const float* self_loop = (const float*)d_in[3];
    const float* norm      = (const float*)d_in[4];
    const int*   src       = (const int*)d_in[5];
    const int*   dst       = (const int*)d_in[6];
    const int*   etype     = (const int*)d_in[7];
    float* out = (float*)d_out;

    char* ws = (char*)d_ws;
    size_t off = 0;
    auto take = [&](size_t bytes) { size_t o = off; off = (off + bytes + 255) & ~(size_t)255; return o; };

    int* dstOff = (int*)(ws + take((NN + 1) * 4));
    int* cursor = (int*)(ws + take((size_t)NN * 4));
    int* hist   = (int*)(ws + take((size_t)NN * 4));
    int* incl   = (int*)(ws + take((size_t)NN * 4));
    int* bsum   = (int*)(ws + take(SCAN_B * 4));
    int* boff   = (int*)(ws + take(SCAN_B * 4));
    int2* rec   = (int2*)(ws + take((size_t)NE * 8));
    unsigned int* Xb = (unsigned int*)(ws + take((size_t)NN * 64 * 4));
    unsigned short* Bt = (unsigned short*)(ws + take((size_t)128 * KTOT * 2));

    size_t avail = (ws_size > off) ? ws_size - off : 0;
    long long cc = (long long)(avail / 2048);   // 2KB per A row
    cc &= ~63LL;                                // multiple of 64 (gemm wave = 64 rows)
    long long nn64 = (NN + 63) & ~63LL;
    if (cc > nn64) cc = nn64;
    if (cc < 64) cc = 64;
    int chunkC = (int)cc;
    unsigned int* A = (unsigned int*)(ws + off);

    hipMemsetAsync(hist, 0, (size_t)NN * 4, stream);
    histD_kernel<<<1024, 256, 0, stream>>>(dst, hist);
    scanA_kernel<<<SCAN_B, 256, 0, stream>>>(hist, incl, bsum);
    scanB_kernel<<<1, 512, 0, stream>>>(bsum, boff);
    scanC_kernel<<<SCAN_B, 256, 0, stream>>>(hist, incl, boff, dstOff, cursor);
    scatterD_kernel<<<1024, 256, 0, stream>>>(src, dst, etype, norm, cursor, rec);
    xbf16_kernel<<<(NN * 64 + 255) / 256, 256, 0, stream>>>(node_feat, Xb);
    buildBt_kernel<<<(128 * KTOT + 255) / 256, 256, 0, stream>>>(weight, self_loop, Bt);

    for (int c0 = 0; c0 < NN; c0 += chunkC) {
        int C = NN - c0; if (C > chunkC) C = chunkC;
        aggregate_kernel<<<(C + 3) / 4, 256, 0, stream>>>(rec, dstOff, Xb, w_coe, A, c0, C);
        int nW = (C + 63) / 64;
        gemm_kernel<<<(nW + 3) / 4, 256, 0, stream>>>((const unsigned short*)A,
                (const unsigned short*)Xb, Bt, out, c0, nW, C);
    }
}